// Round 1
// baseline (408.701 us; speedup 1.0000x reference)
//
#include <hip/hip_runtime.h>
#include <hip/hip_bf16.h>

// images: [B=64, C=3, H=512, W=512] f32
// patches: [B, P=4096, C, 8, 8]; patch p = ph*64 + pw
// contrast[b][p] = (max - min + 1e-8) / (max + min) over 192 elems
// top-512 per image (ties -> lower index), zero the rest, output patch layout.

#define B_IMG 64
#define NPAT 4096      // patches per image (64x64)
#define TOPK 512

// ---------------- Kernel 1: per-patch contrast ----------------
// grid: 4096 blocks = (b, ph); block: 256 threads; 4 threads per patch (pw).
__global__ __launch_bounds__(256) void contrast_kernel(const float* __restrict__ in,
                                                       float* __restrict__ contrast) {
    const int blk = blockIdx.x;
    const int b  = blk >> 6;
    const int ph = blk & 63;
    const int tid = threadIdx.x;
    const int pw  = tid >> 2;   // 0..63
    const int sub = tid & 3;    // 0..3

    float mx = -1e30f, mn = 1e30f;
    // 24 rows total (3 channels x 8 py); this thread handles rows sub*6 .. sub*6+5
    #pragma unroll
    for (int i = 0; i < 6; ++i) {
        const int r  = sub * 6 + i;      // 0..23
        const int c  = r >> 3;           // 0..2
        const int py = r & 7;            // 0..7
        const size_t base = (((size_t)b * 3 + c) * 512 + (size_t)ph * 8 + py) * 512
                          + (size_t)pw * 8;
        const float4* rp = (const float4*)(in + base);
        float4 a = rp[0];
        float4 d = rp[1];
        mx = fmaxf(mx, fmaxf(fmaxf(a.x, a.y), fmaxf(a.z, a.w)));
        mx = fmaxf(mx, fmaxf(fmaxf(d.x, d.y), fmaxf(d.z, d.w)));
        mn = fminf(mn, fminf(fminf(a.x, a.y), fminf(a.z, a.w)));
        mn = fminf(mn, fminf(fminf(d.x, d.y), fminf(d.z, d.w)));
    }
    // reduce across the 4 lanes of this patch (lanes pw*4+sub are contiguous in-wave)
    mx = fmaxf(mx, __shfl_xor(mx, 1));
    mx = fmaxf(mx, __shfl_xor(mx, 2));
    mn = fminf(mn, __shfl_xor(mn, 1));
    mn = fminf(mn, __shfl_xor(mn, 2));

    if (sub == 0) {
        const float ctr = (mx - mn + 1e-8f) / (mx + mn);  // 3 IEEE f32 ops, matches np
        contrast[(size_t)b * NPAT + (size_t)ph * 64 + pw] = ctr;
    }
}

// ---------------- Kernel 2: per-image top-k threshold ----------------
// 64 blocks x 1024 threads. Bitonic sort of 4096 packed keys in LDS.
// key = (float_bits << 32) | (4095 - p): positive floats sort like their bits,
// and on value ties the LOWER patch index gets the LARGER key (jax tie-break).
__global__ __launch_bounds__(1024) void topk_kernel(const float* __restrict__ contrast,
                                                    unsigned long long* __restrict__ thresh) {
    __shared__ unsigned long long sk[NPAT];
    const int b = blockIdx.x;
    const float* row = contrast + (size_t)b * NPAT;
    for (int i = threadIdx.x; i < NPAT; i += blockDim.x) {
        const unsigned int fb = __float_as_uint(row[i]);
        sk[i] = ((unsigned long long)fb << 32) | (unsigned int)(NPAT - 1 - i);
    }
    __syncthreads();

    for (int k = 2; k <= NPAT; k <<= 1) {
        for (int j = k >> 1; j > 0; j >>= 1) {
            for (int t = threadIdx.x; t < NPAT; t += blockDim.x) {
                const int ixj = t ^ j;
                if (ixj > t) {
                    const unsigned long long x = sk[t];
                    const unsigned long long y = sk[ixj];
                    const bool up = ((t & k) == 0);      // ascending segment
                    if ((x > y) == up) { sk[t] = y; sk[ixj] = x; }
                }
            }
            __syncthreads();
        }
    }
    if (threadIdx.x == 0) thresh[b] = sk[NPAT - TOPK];   // 512th largest
}

// ---------------- Kernel 3: masked gather/write ----------------
// grid: 4096 blocks = (b, ph); block: 256 threads.
// Output region for a block: 64 patches * 192 floats = 3072 float4, contiguous.
__global__ __launch_bounds__(256) void write_kernel(const float* __restrict__ in,
                                                    const float* __restrict__ contrast,
                                                    const unsigned long long* __restrict__ thresh,
                                                    float4* __restrict__ out) {
    const int blk = blockIdx.x;
    const int b  = blk >> 6;
    const int ph = blk & 63;

    __shared__ int sel[64];
    if (threadIdx.x < 64) {
        const int p = ph * 64 + threadIdx.x;
        const unsigned int fb = __float_as_uint(contrast[(size_t)b * NPAT + p]);
        const unsigned long long key =
            ((unsigned long long)fb << 32) | (unsigned int)(NPAT - 1 - p);
        sel[threadIdx.x] = (key >= thresh[b]) ? 1 : 0;
    }
    __syncthreads();

    const float4* in4 = (const float4*)in;
    const size_t out_base = ((size_t)b * NPAT + (size_t)ph * 64) * 48;  // float4 units

    #pragma unroll
    for (int it = 0; it < 12; ++it) {
        const int idx = it * 256 + threadIdx.x;   // 0..3071
        const int pl  = idx / 48;                 // local patch 0..63
        const int rem = idx - pl * 48;            // 0..47
        float4 v = make_float4(0.f, 0.f, 0.f, 0.f);
        if (sel[pl]) {
            const int c    = rem >> 4;            // 0..2
            const int t    = rem & 15;
            const int py   = t >> 1;              // 0..7
            const int half = t & 1;               // 0..1
            const size_t a = (((size_t)b * 3 + c) * 512 + (size_t)ph * 8 + py) * 128
                           + (size_t)pl * 2 + half;
            v = in4[a];
        }
        out[out_base + idx] = v;                  // fully coalesced
    }
}

extern "C" void kernel_launch(void* const* d_in, const int* in_sizes, int n_in,
                              void* d_out, int out_size, void* d_ws, size_t ws_size,
                              hipStream_t stream) {
    const float* in = (const float*)d_in[0];
    float* out = (float*)d_out;

    float* contrast = (float*)d_ws;                                   // 64*4096*4 = 1 MB
    unsigned long long* thresh =
        (unsigned long long*)((char*)d_ws + (size_t)B_IMG * NPAT * sizeof(float));

    contrast_kernel<<<B_IMG * 64, 256, 0, stream>>>(in, contrast);
    topk_kernel<<<B_IMG, 1024, 0, stream>>>(contrast, thresh);
    write_kernel<<<B_IMG * 64, 256, 0, stream>>>(in, contrast, thresh, (float4*)out);
}

// Round 2
// 381.001 us; speedup vs baseline: 1.0727x; 1.0727x over previous
//
#include <hip/hip_runtime.h>
#include <hip/hip_bf16.h>

// images: [B=64, C=3, H=512, W=512] f32
// patches: [B, P=4096, C, 8, 8]; patch p = ph*64 + pw
// contrast[b][p] = (max - min + 1e-8) / (max + min) over 192 elems
// top-512 per image (ties -> lower index), zero the rest, output patch layout.

#define B_IMG 64
#define NPAT 4096      // patches per image (64x64)
#define TOPK 512

// ---------------- Kernel 1: per-patch contrast ----------------
// grid: 4096 blocks = (b, ph); block: 256 threads; 4 threads per patch (pw).
__global__ __launch_bounds__(256) void contrast_kernel(const float* __restrict__ in,
                                                       float* __restrict__ contrast) {
    const int blk = blockIdx.x;
    const int b  = blk >> 6;
    const int ph = blk & 63;
    const int tid = threadIdx.x;
    const int pw  = tid >> 2;   // 0..63
    const int sub = tid & 3;    // 0..3

    float mx = -1e30f, mn = 1e30f;
    // 24 rows total (3 channels x 8 py); this thread handles rows sub*6 .. sub*6+5
    #pragma unroll
    for (int i = 0; i < 6; ++i) {
        const int r  = sub * 6 + i;      // 0..23
        const int c  = r >> 3;           // 0..2
        const int py = r & 7;            // 0..7
        const size_t base = (((size_t)b * 3 + c) * 512 + (size_t)ph * 8 + py) * 512
                          + (size_t)pw * 8;
        const float4* rp = (const float4*)(in + base);
        float4 a = rp[0];
        float4 d = rp[1];
        mx = fmaxf(mx, fmaxf(fmaxf(a.x, a.y), fmaxf(a.z, a.w)));
        mx = fmaxf(mx, fmaxf(fmaxf(d.x, d.y), fmaxf(d.z, d.w)));
        mn = fminf(mn, fminf(fminf(a.x, a.y), fminf(a.z, a.w)));
        mn = fminf(mn, fminf(fminf(d.x, d.y), fminf(d.z, d.w)));
    }
    // reduce across the 4 lanes of this patch (lanes pw*4+sub are contiguous in-wave)
    mx = fmaxf(mx, __shfl_xor(mx, 1));
    mx = fmaxf(mx, __shfl_xor(mx, 2));
    mn = fminf(mn, __shfl_xor(mn, 1));
    mn = fminf(mn, __shfl_xor(mn, 2));

    if (sub == 0) {
        const float ctr = (mx - mn + 1e-8f) / (mx + mn);  // 3 IEEE f32 ops, matches np
        contrast[(size_t)b * NPAT + (size_t)ph * 64 + pw] = ctr;
    }
}

// ---------------- Kernel 2: per-image 512th-largest key via binary search ----
// key = (float_bits << 32) | (4095 - p): positive floats sort like their bits,
// and on value ties the LOWER patch index gets the LARGER key (jax tie-break).
// Keys are UNIQUE (index part), so there is a unique T with count(key>=T)==512;
// binary-search T over 63 bits. 16 keys/thread live in registers.
__global__ __launch_bounds__(256) void topk_kernel(const float* __restrict__ contrast,
                                                   unsigned long long* __restrict__ thresh) {
    const int b   = blockIdx.x;
    const int tid = threadIdx.x;
    const float4* row4 = (const float4*)(contrast + (size_t)b * NPAT);

    unsigned long long k[16];
    #pragma unroll
    for (int j = 0; j < 4; ++j) {
        const float4 v = row4[tid * 4 + j];
        const int base = tid * 16 + j * 4;
        k[j * 4 + 0] = ((unsigned long long)__float_as_uint(v.x) << 32) | (unsigned)(NPAT - 1 - (base + 0));
        k[j * 4 + 1] = ((unsigned long long)__float_as_uint(v.y) << 32) | (unsigned)(NPAT - 1 - (base + 1));
        k[j * 4 + 2] = ((unsigned long long)__float_as_uint(v.z) << 32) | (unsigned)(NPAT - 1 - (base + 2));
        k[j * 4 + 3] = ((unsigned long long)__float_as_uint(v.w) << 32) | (unsigned)(NPAT - 1 - (base + 3));
    }

    __shared__ int wsum[4];
    unsigned long long lo = 0ULL;            // count(>=lo) == 4096 >= 512
    unsigned long long hi = 1ULL << 63;      // contrast > 0 => fb < 2^31 => count(>=hi) == 0

    for (int it = 0; it < 63; ++it) {
        const unsigned long long mid = (lo + hi) >> 1;
        int c = 0;
        #pragma unroll
        for (int j = 0; j < 16; ++j) c += (k[j] >= mid) ? 1 : 0;
        // wave-64 reduce
        #pragma unroll
        for (int off = 32; off > 0; off >>= 1) c += __shfl_xor(c, off);
        if ((tid & 63) == 0) wsum[tid >> 6] = c;
        __syncthreads();
        const int total = wsum[0] + wsum[1] + wsum[2] + wsum[3];
        if (total >= TOPK) lo = mid; else hi = mid;
        __syncthreads();   // protect wsum before next iteration's write
    }
    // keys unique => count(>=lo)==512 exactly; lo is the 512th-largest key
    if (tid == 0) thresh[b] = lo;
}

// ---------------- Kernel 3: masked gather/write ----------------
// grid: 4096 blocks = (b, ph); block: 256 threads.
// Output region for a block: 64 patches * 192 floats = 3072 float4, contiguous.
__global__ __launch_bounds__(256) void write_kernel(const float* __restrict__ in,
                                                    const float* __restrict__ contrast,
                                                    const unsigned long long* __restrict__ thresh,
                                                    float4* __restrict__ out) {
    const int blk = blockIdx.x;
    const int b  = blk >> 6;
    const int ph = blk & 63;

    __shared__ int sel[64];
    if (threadIdx.x < 64) {
        const int p = ph * 64 + threadIdx.x;
        const unsigned int fb = __float_as_uint(contrast[(size_t)b * NPAT + p]);
        const unsigned long long key =
            ((unsigned long long)fb << 32) | (unsigned int)(NPAT - 1 - p);
        sel[threadIdx.x] = (key >= thresh[b]) ? 1 : 0;
    }
    __syncthreads();

    const float4* in4 = (const float4*)in;
    const size_t out_base = ((size_t)b * NPAT + (size_t)ph * 64) * 48;  // float4 units

    #pragma unroll
    for (int it = 0; it < 12; ++it) {
        const int idx = it * 256 + threadIdx.x;   // 0..3071
        const int pl  = idx / 48;                 // local patch 0..63
        const int rem = idx - pl * 48;            // 0..47
        float4 v = make_float4(0.f, 0.f, 0.f, 0.f);
        if (sel[pl]) {
            const int c    = rem >> 4;            // 0..2
            const int t    = rem & 15;
            const int py   = t >> 1;              // 0..7
            const int half = t & 1;               // 0..1
            const size_t a = (((size_t)b * 3 + c) * 512 + (size_t)ph * 8 + py) * 128
                           + (size_t)pl * 2 + half;
            v = in4[a];
        }
        out[out_base + idx] = v;                  // fully coalesced
    }
}

extern "C" void kernel_launch(void* const* d_in, const int* in_sizes, int n_in,
                              void* d_out, int out_size, void* d_ws, size_t ws_size,
                              hipStream_t stream) {
    const float* in = (const float*)d_in[0];
    float* out = (float*)d_out;

    float* contrast = (float*)d_ws;                                   // 64*4096*4 = 1 MB
    unsigned long long* thresh =
        (unsigned long long*)((char*)d_ws + (size_t)B_IMG * NPAT * sizeof(float));

    contrast_kernel<<<B_IMG * 64, 256, 0, stream>>>(in, contrast);
    topk_kernel<<<B_IMG, 256, 0, stream>>>(contrast, thresh);
    write_kernel<<<B_IMG * 64, 256, 0, stream>>>(in, contrast, thresh, (float4*)out);
}

// Round 4
// 357.067 us; speedup vs baseline: 1.1446x; 1.0670x over previous
//
#include <hip/hip_runtime.h>
#include <hip/hip_bf16.h>

// images: [B=64, C=3, H=512, W=512] f32
// patches: [B, P=4096, C, 8, 8]; patch p = ph*64 + pw
// contrast[b][p] = (max - min + 1e-8) / (max + min) over 192 elems
// top-512 per image (ties -> lower index), zero the rest, output patch layout.

#define B_IMG 64
#define NPAT 4096      // patches per image (64x64)
#define TOPK 512

typedef float f32x4 __attribute__((ext_vector_type(4)));  // native vec for nt-store

// key packing: contrast bits fb < 2^30 (contrast <= ~1.0), index 12 bits.
// key = (fb << 12) | (4095 - p)  -- 42 bits; larger key = larger contrast,
// ties broken toward LOWER patch index (jax top_k tie-break).
#define KEY_BITS 42

__device__ __forceinline__ unsigned long long make_key(unsigned int fb, int p) {
    return ((unsigned long long)fb << 12) | (unsigned)(NPAT - 1 - p);
}

// ---------------- Kernel 1: per-patch contrast ----------------
// grid: 4096 blocks = (b, ph); block: 256 threads; 4 threads per patch (pw).
__global__ __launch_bounds__(256) void contrast_kernel(const float* __restrict__ in,
                                                       float* __restrict__ contrast) {
    const int blk = blockIdx.x;
    const int b  = blk >> 6;
    const int ph = blk & 63;
    const int tid = threadIdx.x;
    const int pw  = tid >> 2;   // 0..63
    const int sub = tid & 3;    // 0..3

    float mx = -1e30f, mn = 1e30f;
    // 24 rows total (3 channels x 8 py); this thread handles rows sub*6 .. sub*6+5
    #pragma unroll
    for (int i = 0; i < 6; ++i) {
        const int r  = sub * 6 + i;      // 0..23
        const int c  = r >> 3;           // 0..2
        const int py = r & 7;            // 0..7
        const size_t base = (((size_t)b * 3 + c) * 512 + (size_t)ph * 8 + py) * 512
                          + (size_t)pw * 8;
        const float4* rp = (const float4*)(in + base);
        float4 a = rp[0];
        float4 d = rp[1];
        mx = fmaxf(mx, fmaxf(fmaxf(a.x, a.y), fmaxf(a.z, a.w)));
        mx = fmaxf(mx, fmaxf(fmaxf(d.x, d.y), fmaxf(d.z, d.w)));
        mn = fminf(mn, fminf(fminf(a.x, a.y), fminf(a.z, a.w)));
        mn = fminf(mn, fminf(fminf(d.x, d.y), fminf(d.z, d.w)));
    }
    // reduce across the 4 lanes of this patch (lanes pw*4+sub are contiguous in-wave)
    mx = fmaxf(mx, __shfl_xor(mx, 1));
    mx = fmaxf(mx, __shfl_xor(mx, 2));
    mn = fminf(mn, __shfl_xor(mn, 1));
    mn = fminf(mn, __shfl_xor(mn, 2));

    if (sub == 0) {
        const float ctr = (mx - mn + 1e-8f) / (mx + mn);  // 3 IEEE f32 ops, matches np
        contrast[(size_t)b * NPAT + (size_t)ph * 64 + pw] = ctr;
    }
}

// ---------------- Kernel 2: per-image 512th-largest key via binary search ----
// Keys are UNIQUE (index bits), so a unique T exists with count(key>=T)==512;
// binary-search T over 42 bits. 16 keys/thread live in registers.
__global__ __launch_bounds__(256) void topk_kernel(const float* __restrict__ contrast,
                                                   unsigned long long* __restrict__ thresh) {
    const int b   = blockIdx.x;
    const int tid = threadIdx.x;
    const float4* row4 = (const float4*)(contrast + (size_t)b * NPAT);

    unsigned long long k[16];
    #pragma unroll
    for (int j = 0; j < 4; ++j) {
        const float4 v = row4[tid * 4 + j];
        const int base = tid * 16 + j * 4;
        k[j * 4 + 0] = make_key(__float_as_uint(v.x), base + 0);
        k[j * 4 + 1] = make_key(__float_as_uint(v.y), base + 1);
        k[j * 4 + 2] = make_key(__float_as_uint(v.z), base + 2);
        k[j * 4 + 3] = make_key(__float_as_uint(v.w), base + 3);
    }

    __shared__ int wsum[4];
    unsigned long long lo = 0ULL;               // count(>=lo) == 4096 >= 512
    unsigned long long hi = 1ULL << KEY_BITS;   // count(>=hi) == 0

    for (int it = 0; it < KEY_BITS; ++it) {
        const unsigned long long mid = (lo + hi) >> 1;
        int c = 0;
        #pragma unroll
        for (int j = 0; j < 16; ++j) c += (k[j] >= mid) ? 1 : 0;
        // wave-64 reduce
        #pragma unroll
        for (int off = 32; off > 0; off >>= 1) c += __shfl_xor(c, off);
        if ((tid & 63) == 0) wsum[tid >> 6] = c;
        __syncthreads();
        const int total = wsum[0] + wsum[1] + wsum[2] + wsum[3];
        if (total >= TOPK) lo = mid; else hi = mid;
        __syncthreads();   // protect wsum before next iteration's write
    }
    // keys unique => count(>=lo)==512 exactly; lo is the 512th-largest key
    if (tid == 0) thresh[b] = lo;
}

// ---------------- Kernel 3: masked gather/write ----------------
// grid: 4096 blocks = (b, ph); block: 256 threads.
// Output region for a block: 64 patches * 192 floats = 3072 float4, contiguous.
// Output stores are NON-TEMPORAL: output is never re-read, and bypassing the
// caches keeps the 201 MB input L3-resident for the selected-patch gather.
__global__ __launch_bounds__(256) void write_kernel(const float* __restrict__ in,
                                                    const float* __restrict__ contrast,
                                                    const unsigned long long* __restrict__ thresh,
                                                    f32x4* __restrict__ out) {
    const int blk = blockIdx.x;
    const int b  = blk >> 6;
    const int ph = blk & 63;

    __shared__ int sel[64];
    if (threadIdx.x < 64) {
        const int p = ph * 64 + threadIdx.x;
        const unsigned int fb = __float_as_uint(contrast[(size_t)b * NPAT + p]);
        sel[threadIdx.x] = (make_key(fb, p) >= thresh[b]) ? 1 : 0;
    }
    __syncthreads();

    const f32x4* in4 = (const f32x4*)in;
    const size_t out_base = ((size_t)b * NPAT + (size_t)ph * 64) * 48;  // float4 units

    #pragma unroll
    for (int it = 0; it < 12; ++it) {
        const int idx = it * 256 + threadIdx.x;   // 0..3071
        const int pl  = idx / 48;                 // local patch 0..63
        const int rem = idx - pl * 48;            // 0..47
        f32x4 v = (f32x4){0.f, 0.f, 0.f, 0.f};
        if (sel[pl]) {
            const int c    = rem >> 4;            // 0..2
            const int t    = rem & 15;
            const int py   = t >> 1;              // 0..7
            const int half = t & 1;               // 0..1
            const size_t a = (((size_t)b * 3 + c) * 512 + (size_t)ph * 8 + py) * 128
                           + (size_t)pl * 2 + half;
            v = in4[a];
        }
        __builtin_nontemporal_store(v, &out[out_base + idx]);  // coalesced, nt
    }
}

extern "C" void kernel_launch(void* const* d_in, const int* in_sizes, int n_in,
                              void* d_out, int out_size, void* d_ws, size_t ws_size,
                              hipStream_t stream) {
    const float* in = (const float*)d_in[0];
    float* out = (float*)d_out;

    float* contrast = (float*)d_ws;                                   // 64*4096*4 = 1 MB
    unsigned long long* thresh =
        (unsigned long long*)((char*)d_ws + (size_t)B_IMG * NPAT * sizeof(float));

    contrast_kernel<<<B_IMG * 64, 256, 0, stream>>>(in, contrast);
    topk_kernel<<<B_IMG, 256, 0, stream>>>(contrast, thresh);
    write_kernel<<<B_IMG * 64, 256, 0, stream>>>(in, contrast, thresh, (f32x4*)out);
}